// Round 5
// baseline (180.695 us; speedup 1.0000x reference)
//
#include <hip/hip_runtime.h>
#include <hip/hip_cooperative_groups.h>

namespace cg = cooperative_groups;

#define D 128
#define BATCH 16384
#define NROWS 16512     // 16384 T-rows + 128 B-rows
#define GRID 512
#define NTILES (BATCH / 16)

typedef float f32x4 __attribute__((ext_vector_type(4)));
typedef short bh8 __attribute__((ext_vector_type(8)));

__device__ __forceinline__ unsigned short f2bf(float f) {
    unsigned u = __float_as_uint(f);
    u += 0x7FFFu + ((u >> 16) & 1u);   // round-to-nearest-even
    return (unsigned short)(u >> 16);
}

// Single cooperative kernel, 3 phases separated by grid.sync():
//  P1: M[R] = dot(row R of [T(16384 rows); B(128 rows)], tv)
//  P2: W2T[j][x] = bf16(dot(M[x,:], op_w[j,:]));  bias2[j] = dot(mB, op_w[j,:]) + op_b[j]
//  P3: out[b,j] = sum_x we[idx[b],x]*W2[x,j] + bias2[j]  (bf16 MFMA, 16-row tiles)
__global__ __launch_bounds__(256, 2) void fused(
    const int* __restrict__ idx, const float* __restrict__ we,
    const float* __restrict__ T, const float* __restrict__ Bm,
    const float* __restrict__ tv, const float* __restrict__ op_w,
    const float* __restrict__ op_b, float* __restrict__ M,
    unsigned short* __restrict__ W2T, float* __restrict__ bias2,
    float* __restrict__ out)
{
    cg::grid_group grid = cg::this_grid();
    const int t = threadIdx.x;
    const int l = t & 31;        // lane in 32-group
    const int rg = t >> 5;       // group 0..7
    const int bid = blockIdx.x;  // 0..GRID-1

    const f32x4 tvv = *(const f32x4*)(tv + l * 4);

    // ---- Phase 1: 16512 coalesced 128-dots, grid-strided ----
    for (int R = bid * 8 + rg; R < NROWS; R += GRID * 8) {
        const float* src = (R < BATCH) ? (T + (size_t)R * D)
                                       : (Bm + (size_t)(R - BATCH) * D);
        f32x4 a = *(const f32x4*)(src + l * 4);
        float p = a[0]*tvv[0] + a[1]*tvv[1] + a[2]*tvv[2] + a[3]*tvv[3];
#pragma unroll
        for (int s = 16; s >= 1; s >>= 1) p += __shfl_xor(p, s, 32);
        if (l == 0) M[R] = p;
    }
    __threadfence();
    grid.sync();

    // ---- Phase 2: W2T + bias2, 16512 more 128-dots ----
    for (int e = bid * 8 + rg; e < NROWS; e += GRID * 8) {
        const float* mrow;
        int j;
        if (e < 16384) { mrow = M + (size_t)(e >> 7) * D; j = e & 127; }
        else           { mrow = M + 16384;                j = e - 16384; }
        f32x4 a = *(const f32x4*)(mrow + l * 4);
        f32x4 b = *(const f32x4*)(op_w + (size_t)j * D + l * 4);
        float p = a[0]*b[0] + a[1]*b[1] + a[2]*b[2] + a[3]*b[3];
#pragma unroll
        for (int s = 16; s >= 1; s >>= 1) p += __shfl_xor(p, s, 32);
        if (l == 0) {
            if (e < 16384) W2T[(size_t)j * D + (e >> 7)] = f2bf(p);
            else           bias2[j] = p + op_b[j];
        }
    }
    __threadfence();
    grid.sync();

    // ---- Phase 3: MFMA gather-GEMM, 2 tiles per block ----
    const int wv = t >> 6;            // column quarter 0..3
    const int ll = t & 63;
    const int l15 = ll & 15, lg = ll >> 4;

    for (int tile = bid; tile < NTILES; tile += GRID) {
        const int b0 = tile * 16;
        const int g = idx[b0 + l15];

        bh8 bfr[2][4];
#pragma unroll
        for (int c = 0; c < 2; ++c) {
            const int j = wv * 32 + c * 16 + l15;
#pragma unroll
            for (int s = 0; s < 4; ++s)
                bfr[c][s] = *(const bh8*)(W2T + (size_t)j * D + s * 32 + lg * 8);
        }
        float bias[2];
#pragma unroll
        for (int c = 0; c < 2; ++c) bias[c] = bias2[wv * 32 + c * 16 + l15];

        const float* arow = we + (size_t)g * D;
        f32x4 a[8];
#pragma unroll
        for (int s = 0; s < 4; ++s) {
            a[2*s]   = *(const f32x4*)(arow + s * 32 + lg * 8);
            a[2*s+1] = *(const f32x4*)(arow + s * 32 + lg * 8 + 4);
        }
        bh8 af[4];
#pragma unroll
        for (int s = 0; s < 4; ++s) {
            af[s][0] = (short)f2bf(a[2*s][0]);   af[s][1] = (short)f2bf(a[2*s][1]);
            af[s][2] = (short)f2bf(a[2*s][2]);   af[s][3] = (short)f2bf(a[2*s][3]);
            af[s][4] = (short)f2bf(a[2*s+1][0]); af[s][5] = (short)f2bf(a[2*s+1][1]);
            af[s][6] = (short)f2bf(a[2*s+1][2]); af[s][7] = (short)f2bf(a[2*s+1][3]);
        }

        f32x4 acc[2];
#pragma unroll
        for (int c = 0; c < 2; ++c) acc[c] = (f32x4){0.f, 0.f, 0.f, 0.f};
#pragma unroll
        for (int s = 0; s < 4; ++s)
#pragma unroll
            for (int c = 0; c < 2; ++c)
                acc[c] = __builtin_amdgcn_mfma_f32_16x16x32_bf16(af[s], bfr[c][s], acc[c], 0, 0, 0);

#pragma unroll
        for (int c = 0; c < 2; ++c)
#pragma unroll
            for (int r = 0; r < 4; ++r)
                out[(size_t)(b0 + lg * 4 + r) * D + wv * 32 + c * 16 + l15] = acc[c][r] + bias[c];
    }
}

extern "C" void kernel_launch(void* const* d_in, const int* in_sizes, int n_in,
                              void* d_out, int out_size, void* d_ws, size_t ws_size,
                              hipStream_t stream) {
    const int*   idx     = (const int*)d_in[0];
    const float* w_embed = (const float*)d_in[1];
    const float* T       = (const float*)d_in[2];
    const float* Bm      = (const float*)d_in[3];
    const float* tv      = (const float*)d_in[4];
    const float* op_w    = (const float*)d_in[5];
    const float* op_b    = (const float*)d_in[6];
    float* out = (float*)d_out;

    // ws layout: M[16512] f32 (66048 B) | W2T[128*128] bf16 (32768 B) | bias2[128] f32
    float* M = (float*)d_ws;
    unsigned short* W2T = (unsigned short*)((char*)d_ws + 66048);
    float* bias2 = (float*)((char*)d_ws + 66048 + 32768);

    void* args[] = {(void*)&idx, (void*)&w_embed, (void*)&T, (void*)&Bm,
                    (void*)&tv, (void*)&op_w, (void*)&op_b, (void*)&M,
                    (void*)&W2T, (void*)&bias2, (void*)&out};
    hipLaunchCooperativeKernel((const void*)fused, dim3(GRID), dim3(256),
                               args, 0, stream);
}

// Round 6
// 22.034 us; speedup vs baseline: 8.2007x; 8.2007x over previous
//
#include <hip/hip_runtime.h>

#define D 128
#define BATCH 16384

typedef float f32x4 __attribute__((ext_vector_type(4)));
typedef short bh8 __attribute__((ext_vector_type(8)));

__device__ __forceinline__ unsigned short f2bf(float f) {
    unsigned u = __float_as_uint(f);
    u += 0x7FFFu + ((u >> 16) & 1u);   // round-to-nearest-even
    return (unsigned short)(u >> 16);
}

// Fused prep, lean version: block x in [0,128]:
//   x < 128: W2T[j][x] = bf16( sum_y (sum_z T[x,y,z] tv[z]) * op_w[j,y] )
//   x ==128: bias2[j]  =       sum_y (sum_z B[y,z]  tv[z]) * op_w[j,y] + op_b[j]
// m computed straight from global (coalesced 32-lane rows); only op_w staged in LDS.
__global__ __launch_bounds__(512) void prep(
    const float* __restrict__ T, const float* __restrict__ Bm,
    const float* __restrict__ tv, const float* __restrict__ op_w,
    const float* __restrict__ op_b, unsigned short* __restrict__ W2T,
    float* __restrict__ bias2)
{
    __shared__ float ws[D * D];   // op_w, row-major (64 KB)
    __shared__ float m_s[D];
    const int x = blockIdx.x;
    const int t = threadIdx.x;    // 0..511
    const int l = t & 31;         // lane in 32-group
    const int rg = t >> 5;        // row group 0..15

    const float* src = (x < D) ? (T + (size_t)x * D * D) : Bm;
    const f32x4 tvv = *(const f32x4*)(tv + l * 4);

    // m[y] = dot(src[y,:], tv): 16 rows in flight, 8 passes, coalesced
#pragma unroll
    for (int yi = 0; yi < 8; ++yi) {
        const int y = yi * 16 + rg;
        f32x4 a = *(const f32x4*)(src + (size_t)y * D + l * 4);
        float p = a[0]*tvv[0] + a[1]*tvv[1] + a[2]*tvv[2] + a[3]*tvv[3];
#pragma unroll
        for (int s = 16; s >= 1; s >>= 1) p += __shfl_xor(p, s, 32);
        if (l == 0) m_s[y] = p;
    }
    // stage op_w (L2-hot after block 0) — 8 f32x4 per thread, coalesced
#pragma unroll
    for (int i = 0; i < 8; ++i)
        ((f32x4*)ws)[t + i * 512] = ((const f32x4*)op_w)[t + i * 512];
    __syncthreads();

    const f32x4 mv = *(const f32x4*)&m_s[l * 4];
#pragma unroll
    for (int ji = 0; ji < 8; ++ji) {
        const int j = ji * 16 + rg;
        f32x4 w = *(const f32x4*)&ws[j * D + l * 4];
        float p = w[0]*mv[0] + w[1]*mv[1] + w[2]*mv[2] + w[3]*mv[3];
#pragma unroll
        for (int s = 16; s >= 1; s >>= 1) p += __shfl_xor(p, s, 32);
        if (l == 0) {
            if (x < D) W2T[j * D + x] = f2bf(p);
            else       bias2[j] = p + op_b[j];
        }
    }
}

// Main: out[b,j] = sum_x we[idx[b],x] * W2[x,j] + bias2[j] via bf16 MFMA.
// 1024 blocks x 256 threads (4 waves). All 4 waves share the block's 16 rows
// (A-gather L1-shared); wave wv owns column quarter wv*32 (2 MFMA col-tiles).
__global__ __launch_bounds__(256) void main_mfma(
    const int* __restrict__ idx, const float* __restrict__ we,
    const unsigned short* __restrict__ W2T, const float* __restrict__ bias2,
    float* __restrict__ out)
{
    const int t = threadIdx.x;
    const int wv = t >> 6;            // column quarter 0..3
    const int l = t & 63;
    const int l15 = l & 15, lg = l >> 4;
    const int b0 = blockIdx.x * 16;

    const int g = idx[b0 + l15];

    // B: 8 x bh8 from col-major W2T (L2/L3-resident 32 KB) — independent, issue first
    bh8 bfr[2][4];
#pragma unroll
    for (int c = 0; c < 2; ++c) {
        const int j = wv * 32 + c * 16 + l15;
#pragma unroll
        for (int s = 0; s < 4; ++s)
            bfr[c][s] = *(const bh8*)(W2T + (size_t)j * D + s * 32 + lg * 8);
    }
    float bias[2];
#pragma unroll
    for (int c = 0; c < 2; ++c) bias[c] = bias2[wv * 32 + c * 16 + l15];

    // A: gather 8 x f32x4 (full 128-k row slice for this lane)
    const float* arow = we + (size_t)g * D;
    f32x4 a[8];
#pragma unroll
    for (int s = 0; s < 4; ++s) {
        a[2*s]   = *(const f32x4*)(arow + s * 32 + lg * 8);
        a[2*s+1] = *(const f32x4*)(arow + s * 32 + lg * 8 + 4);
    }

    bh8 af[4];
#pragma unroll
    for (int s = 0; s < 4; ++s) {
        af[s][0] = (short)f2bf(a[2*s][0]);   af[s][1] = (short)f2bf(a[2*s][1]);
        af[s][2] = (short)f2bf(a[2*s][2]);   af[s][3] = (short)f2bf(a[2*s][3]);
        af[s][4] = (short)f2bf(a[2*s+1][0]); af[s][5] = (short)f2bf(a[2*s+1][1]);
        af[s][6] = (short)f2bf(a[2*s+1][2]); af[s][7] = (short)f2bf(a[2*s+1][3]);
    }

    f32x4 acc[2];
#pragma unroll
    for (int c = 0; c < 2; ++c) acc[c] = (f32x4){0.f, 0.f, 0.f, 0.f};
#pragma unroll
    for (int s = 0; s < 4; ++s)
#pragma unroll
        for (int c = 0; c < 2; ++c)
            acc[c] = __builtin_amdgcn_mfma_f32_16x16x32_bf16(af[s], bfr[c][s], acc[c], 0, 0, 0);

#pragma unroll
    for (int c = 0; c < 2; ++c)
#pragma unroll
        for (int r = 0; r < 4; ++r)
            out[(size_t)(b0 + lg * 4 + r) * D + wv * 32 + c * 16 + l15] = acc[c][r] + bias[c];
}

extern "C" void kernel_launch(void* const* d_in, const int* in_sizes, int n_in,
                              void* d_out, int out_size, void* d_ws, size_t ws_size,
                              hipStream_t stream) {
    const int*   idx     = (const int*)d_in[0];
    const float* w_embed = (const float*)d_in[1];
    const float* T       = (const float*)d_in[2];
    const float* Bm      = (const float*)d_in[3];
    const float* tv      = (const float*)d_in[4];
    const float* op_w    = (const float*)d_in[5];
    const float* op_b    = (const float*)d_in[6];
    float* out = (float*)d_out;

    unsigned short* W2T = (unsigned short*)d_ws;              // 32768 B
    float* bias2 = (float*)((char*)d_ws + 32768);             // 512 B

    prep<<<D + 1, 512, 0, stream>>>(T, Bm, tv, op_w, op_b, W2T, bias2);
    main_mfma<<<BATCH / 16, 256, 0, stream>>>(idx, w_embed, W2T, bias2, out);
}